// Round 2
// baseline (111.341 us; speedup 1.0000x reference)
//
#include <hip/hip_runtime.h>

// Mixture-of-64-tiny-experts, fp32, per sample:
//   h[s] = tanhshrink(W1[s]@x + b1[s]); o[s] = tanh(W2[s]@h + b2[s])
//   gate = softmax(Gw2 @ tanhshrink(Gw1@x+Gb1) + Gb2); out = sum gate[s]*o[s]
//
// R1 theory: trans pipe (v_exp/v_rcp, ~16cyc/wave64) was ~60% of busy time.
// Replace exp-based tanh with Pade[5/4] + bit-hack-Newton reciprocal:
// zero trans ops per tanh (only softmax exp remains on the trans pipe).

#define NSUB 64

__device__ __forceinline__ float fast_exp(float x) {
    return __builtin_amdgcn_exp2f(x * 1.4426950408889634f);
}

// positive-input fast reciprocal: bit-hack seed + 2 Newton iters (~1e-4 rel)
__device__ __forceinline__ float fast_rcp_pos(float d) {
    float r = __int_as_float(0x7EF311C3 - __float_as_int(d));
    r = r * fmaf(-d, r, 2.0f);
    r = r * fmaf(-d, r, 2.0f);
    return r;
}

// tanh via continued-fraction Pade [5/4], clamped. Max abs err ~1.2e-3 (x~3.7).
// tanh(x) = x*(945 + 105 t + t^2) / (945 + 420 t + 15 t^2),  t = x^2
__device__ __forceinline__ float tanh_pade(float x) {
    float t = x * x;
    float n = fmaf(t, t + 105.0f, 945.0f);
    float d = fmaf(t, fmaf(t, 15.0f, 420.0f), 945.0f);
    float r = x * n * fast_rcp_pos(d);
    return __builtin_amdgcn_fmed3f(r, -1.0f, 1.0f);
}

__global__ __launch_bounds__(256) void moe_kernel(
    const float* __restrict__ x,
    const float* __restrict__ W1, const float* __restrict__ b1,
    const float* __restrict__ W2, const float* __restrict__ b2,
    const float* __restrict__ Gw1, const float* __restrict__ Gb1,
    const float* __restrict__ Gw2, const float* __restrict__ Gb2,
    float* __restrict__ out)
{
    int t = blockIdx.x * blockDim.x + threadIdx.x;
    long base = (long)t * 12;

    const float4* xv = (const float4*)(x + base);
    float4 a0 = xv[0];
    float4 a1 = xv[1];
    float4 a2 = xv[2];
    float xa[6] = {a0.x, a0.y, a0.z, a0.w, a1.x, a1.y};
    float xb[6] = {a1.z, a1.w, a2.x, a2.y, a2.z, a2.w};

    // ---- gating hidden: g = tanhshrink(Gw1 @ x + Gb1) ----
    float ga[6], gb[6];
#pragma unroll
    for (int j = 0; j < 6; ++j) {
        float bias = Gb1[j];
        float sa = bias, sb = bias;
#pragma unroll
        for (int i = 0; i < 6; ++i) {
            float w = Gw1[j * 6 + i];
            sa = fmaf(w, xa[i], sa);
            sb = fmaf(w, xb[i], sb);
        }
        ga[j] = sa - tanh_pade(sa);
        gb[j] = sb - tanh_pade(sb);
    }

    // ---- subnet loop with fused softmax numerator/denominator ----
    float acc0a = 0.f, acc1a = 0.f, accEa = 0.f;
    float acc0b = 0.f, acc1b = 0.f, accEb = 0.f;

#pragma unroll 2
    for (int s = 0; s < NSUB; ++s) {
        const float* w1 = W1 + s * 24;  // [4][6]
        float ha[4], hb[4];
#pragma unroll
        for (int j = 0; j < 4; ++j) {
            float bias = b1[s * 4 + j];
            float sa = bias, sb = bias;
#pragma unroll
            for (int i = 0; i < 6; ++i) {
                float w = w1[j * 6 + i];
                sa = fmaf(w, xa[i], sa);
                sb = fmaf(w, xb[i], sb);
            }
            ha[j] = sa - tanh_pade(sa);   // tanhshrink
            hb[j] = sb - tanh_pade(sb);
        }

        float oa[2], ob[2];
#pragma unroll
        for (int o = 0; o < 2; ++o) {
            float bias = b2[s * 2 + o];
            float sa = bias, sb = bias;
#pragma unroll
            for (int j = 0; j < 4; ++j) {
                float w = W2[s * 8 + o * 4 + j];
                sa = fmaf(w, ha[j], sa);
                sb = fmaf(w, hb[j], sb);
            }
            oa[o] = tanh_pade(sa);
            ob[o] = tanh_pade(sb);
        }

        // gate logit; softmax via running numerator/denominator
        float la = Gb2[s], lb = la;
#pragma unroll
        for (int j = 0; j < 6; ++j) {
            float w = Gw2[s * 6 + j];
            la = fmaf(w, ga[j], la);
            lb = fmaf(w, gb[j], lb);
        }
        float ea = fast_exp(la);
        float eb = fast_exp(lb);
        accEa += ea;
        accEb += eb;
        acc0a = fmaf(ea, oa[0], acc0a);
        acc1a = fmaf(ea, oa[1], acc1a);
        acc0b = fmaf(eb, ob[0], acc0b);
        acc1b = fmaf(eb, ob[1], acc1b);
    }

    float ra = fast_rcp_pos(accEa);
    float rb = fast_rcp_pos(accEb);
    float4 r;
    r.x = acc0a * ra;
    r.y = acc1a * ra;
    r.z = acc0b * rb;
    r.w = acc1b * rb;
    ((float4*)&out[(long)t * 4])[0] = r;
}

extern "C" void kernel_launch(void* const* d_in, const int* in_sizes, int n_in,
                              void* d_out, int out_size, void* d_ws, size_t ws_size,
                              hipStream_t stream) {
    const float* x   = (const float*)d_in[0];
    const float* W1  = (const float*)d_in[1];
    const float* b1  = (const float*)d_in[2];
    const float* W2  = (const float*)d_in[3];
    const float* b2  = (const float*)d_in[4];
    const float* Gw1 = (const float*)d_in[5];
    const float* Gb1 = (const float*)d_in[6];
    const float* Gw2 = (const float*)d_in[7];
    const float* Gb2 = (const float*)d_in[8];
    float* out = (float*)d_out;

    const int threads = 256;
    const int blocks = (524288 / 2) / threads;  // 1024
    moe_kernel<<<blocks, threads, 0, stream>>>(x, W1, b1, W2, b2, Gw1, Gb1, Gw2, Gb2, out);
}

// Round 3
// 83.309 us; speedup vs baseline: 1.3365x; 1.3365x over previous
//
#include <hip/hip_runtime.h>

// Mixture-of-64-tiny-experts, fp32, per sample:
//   h[s] = tanhshrink(W1[s]@x + b1[s]); o[s] = tanh(W2[s]@h + b2[s])
//   gate = softmax(Gw2 @ tanhshrink(Gw1@x+Gb1) + Gb2); out = sum gate[s]*o[s]
//
// R2: trans pipe proved free (R1 Pade regression) -> keep exp2/rcp tanh.
// Switch to 1 sample/thread: halves register live-set (kills remat pressure),
// doubles waves/SIMD to 8 (hides s_load latency of per-subnet weights).

#define NSUB 64

// tanhshrink(a) = a - tanh(a) = (a-1) + 2/(exp2(2*log2e*a)+1)
__device__ __forceinline__ float tanhshrink_fast(float a) {
    float e = __builtin_amdgcn_exp2f(a * 2.8853900817779268f);
    float r = __builtin_amdgcn_rcpf(e + 1.0f);
    return fmaf(2.0f, r, a - 1.0f);
}

// tanh(a) = 1 - 2/(exp2(2*log2e*a)+1)
__device__ __forceinline__ float tanh_fast(float a) {
    float e = __builtin_amdgcn_exp2f(a * 2.8853900817779268f);
    float r = __builtin_amdgcn_rcpf(e + 1.0f);
    return fmaf(-2.0f, r, 1.0f);
}

__device__ __forceinline__ float fast_exp(float x) {
    return __builtin_amdgcn_exp2f(x * 1.4426950408889634f);
}

__global__ __launch_bounds__(256) void moe_kernel(
    const float* __restrict__ x,
    const float* __restrict__ W1, const float* __restrict__ b1,
    const float* __restrict__ W2, const float* __restrict__ b2,
    const float* __restrict__ Gw1, const float* __restrict__ Gb1,
    const float* __restrict__ Gw2, const float* __restrict__ Gb2,
    float* __restrict__ out)
{
    int t = blockIdx.x * blockDim.x + threadIdx.x;

    // 6 floats/thread at 24B stride: only 8B-aligned -> three float2 loads.
    const float2* xv = (const float2*)(x + (long)t * 6);
    float2 p0 = xv[0];
    float2 p1 = xv[1];
    float2 p2 = xv[2];
    float xa[6] = {p0.x, p0.y, p1.x, p1.y, p2.x, p2.y};

    // ---- gating hidden: g = tanhshrink(Gw1 @ x + Gb1) ----
    float ga[6];
#pragma unroll
    for (int j = 0; j < 6; ++j) {
        float sa = Gb1[j];
#pragma unroll
        for (int i = 0; i < 6; ++i)
            sa = fmaf(Gw1[j * 6 + i], xa[i], sa);
        ga[j] = tanhshrink_fast(sa);
    }

    // ---- subnet loop, softmax folded into running numerator/denominator ----
    float acc0 = 0.f, acc1 = 0.f, accE = 0.f;

#pragma unroll 2
    for (int s = 0; s < NSUB; ++s) {
        const float* w1 = W1 + s * 24;  // [4][6]
        float h[4];
#pragma unroll
        for (int j = 0; j < 4; ++j) {
            float sa = b1[s * 4 + j];
#pragma unroll
            for (int i = 0; i < 6; ++i)
                sa = fmaf(w1[j * 6 + i], xa[i], sa);
            h[j] = tanhshrink_fast(sa);
        }

        float o0 = b2[s * 2 + 0], o1 = b2[s * 2 + 1];
#pragma unroll
        for (int j = 0; j < 4; ++j) {
            o0 = fmaf(W2[s * 8 + j], h[j], o0);
            o1 = fmaf(W2[s * 8 + 4 + j], h[j], o1);
        }
        o0 = tanh_fast(o0);
        o1 = tanh_fast(o1);

        float la = Gb2[s];
#pragma unroll
        for (int j = 0; j < 6; ++j)
            la = fmaf(Gw2[s * 6 + j], ga[j], la);
        float ea = fast_exp(la);   // |logit| small; no max-subtract needed
        accE += ea;
        acc0 = fmaf(ea, o0, acc0);
        acc1 = fmaf(ea, o1, acc1);
    }

    float ra = __builtin_amdgcn_rcpf(accE);
    float2 r;
    r.x = acc0 * ra;
    r.y = acc1 * ra;
    ((float2*)&out[(long)t * 2])[0] = r;
}

extern "C" void kernel_launch(void* const* d_in, const int* in_sizes, int n_in,
                              void* d_out, int out_size, void* d_ws, size_t ws_size,
                              hipStream_t stream) {
    const float* x   = (const float*)d_in[0];
    const float* W1  = (const float*)d_in[1];
    const float* b1  = (const float*)d_in[2];
    const float* W2  = (const float*)d_in[3];
    const float* b2  = (const float*)d_in[4];
    const float* Gw1 = (const float*)d_in[5];
    const float* Gb1 = (const float*)d_in[6];
    const float* Gw2 = (const float*)d_in[7];
    const float* Gb2 = (const float*)d_in[8];
    float* out = (float*)d_out;

    // 524288 samples, 1 per thread -> 2048 blocks of 256 (8 blocks/CU, 100% occ)
    const int threads = 256;
    const int blocks = 524288 / threads;  // 2048
    moe_kernel<<<blocks, threads, 0, stream>>>(x, W1, b1, W2, b2, Gw1, Gb1, Gw2, Gb2, out);
}